// Round 9
// baseline (702.161 us; speedup 1.0000x reference)
//
#include <hip/hip_runtime.h>
#include <math.h>

#define NB     16
#define NCIN   384
#define NHD    24
#define NDIM   96
#define NSTR   5
#define NDT    480

// ===========================================================================
// PLAN A: single cooperative kernel, 768 blocks (3/CU), 256 threads.
// block g: b = g>>  (batch via g/48), sub = g%48.
// A: pool (no LDS/sync; wave-slot -> 2 planes)               -> x8[b]
// B: proj tiles (64 tiles strided over 48 blocks)            -> y8[b]
// C: (sub<4) cluster head=sub                                -> o8[b]
// D: proj2 + upsample (64 o-tiles of 6 strided over 48)      -> out[b]
// Per-batch barriers (48 blocks) via device-scope atomics in ws.
// LDS union: 7824 floats (31.3 KB) -> 3/CU = 94 KB of 160 KB (safe margin).
// PLAN B (fallback if coop launch is rejected): proven 4-kernel pipeline.
// ===========================================================================

__device__ __forceinline__ void group_barrier(int* c, int target) {
    __threadfence();
    __syncthreads();
    if (threadIdx.x == 0) {
        __hip_atomic_fetch_add(c, 1, __ATOMIC_RELEASE, __HIP_MEMORY_SCOPE_AGENT);
        while (__hip_atomic_load(c, __ATOMIC_ACQUIRE, __HIP_MEMORY_SCOPE_AGENT) < target)
            __builtin_amdgcn_s_sleep(2);
    }
    __syncthreads();
    __threadfence();
}

__global__ void __launch_bounds__(256, 3) k_fused(const float* __restrict__ x,
                                                  const float* __restrict__ W1,
                                                  const float* __restrict__ b1,
                                                  const float* __restrict__ W2,
                                                  const float* __restrict__ b2,
                                                  const float* __restrict__ salpha,
                                                  const float* __restrict__ sbeta,
                                                  float* __restrict__ out,
                                                  float* __restrict__ x8,
                                                  float* __restrict__ y8,
                                                  float* __restrict__ o8,
                                                  int* __restrict__ flags) {
    __shared__ __align__(16) float smem[7824];
    const int g   = blockIdx.x;
    const int b   = g / 48;
    const int sub = g - b * 48;
    const int tid = threadIdx.x;
    int* cnt = flags + b * 3;

    // ================= Phase A: pool (no LDS, no sync) =================
    {
        const int ws   = sub * 4 + (tid >> 6);   // 0..191 wave-slot in batch
        const int lane = tid & 63;
        const int py = lane >> 3, px = lane & 7;
#pragma unroll
        for (int r = 0; r < 2; ++r) {
            const int c = ws + r * 192;
            const float* base = x + ((size_t)(b * 384 + c)) * 4096 + py * 512 + px * 8;
            float acc = 0.f;
#pragma unroll
            for (int rr = 0; rr < 8; ++rr) {
                float4 a = *reinterpret_cast<const float4*>(base + rr * 64);
                float4 v = *reinterpret_cast<const float4*>(base + rr * 64 + 4);
                acc += a.x + a.y + a.z + a.w + v.x + v.y + v.z + v.w;
            }
            x8[(size_t)(b * 384 + c) * 64 + lane] = acc * (1.f / 64.f);
        }
    }
    group_barrier(cnt + 0, 48);

    // ================= Phase B: proj (tiles strided over 48 blocks) =======
    // tile t: d0=(t&7)*64, pix0=(t>>3)*8. og = tid>>5 (8-way K-split),
    // lt = tid&31: pxg=(lt&1)*4 (4 pix), dg=(lt>>1)*4 (4 d) -> 16 acc.
    {
        #define BAL(c,p) smem[(c)*8+(p)]             // [64][8]   @0..512
        #define BBL(c,d) smem[512+(c)*64+(d)]        // [64][64]  @512..4608
        const int og = tid >> 5, lt = tid & 31;
        const int pxg = (lt & 1) * 4, dg = (lt >> 1) * 4;
        for (int t = sub; t < 64; t += 48) {
            const int d0   = (t & 7) * 64;
            const int pix0 = (t >> 3) * 8;
            float acc[4][4] = {};
            for (int c0 = 0; c0 < 384; c0 += 64) {
                __syncthreads();
                if (tid < 128) {   // BAL: 128 float4
                    int c = tid >> 1, q = tid & 1;
                    *reinterpret_cast<float4*>(&BAL(c, q * 4)) =
                        *reinterpret_cast<const float4*>(&x8[(size_t)(b * 384 + c0 + c) * 64 + pix0 + q * 4]);
                }
#pragma unroll
                for (int i = 0; i < 4; ++i) {   // BBL: 1024 float4
                    int f = tid + i * 256;
                    int c = f >> 4, jg = f & 15;
                    int d = d0 + jg * 4;
                    float4 v = make_float4(0.f, 0.f, 0.f, 0.f);
                    if (d < NDT) v = *reinterpret_cast<const float4*>(&W1[(c0 + c) * NDT + d]);
                    *reinterpret_cast<float4*>(&BBL(c, jg * 4)) = v;
                }
                __syncthreads();
#pragma unroll
                for (int cc = 0; cc < 8; ++cc) {
                    int c = og * 8 + cc;
                    float4 a = *reinterpret_cast<const float4*>(&BAL(c, pxg));
                    float4 w = *reinterpret_cast<const float4*>(&BBL(c, dg));
                    acc[0][0] += a.x * w.x; acc[0][1] += a.x * w.y; acc[0][2] += a.x * w.z; acc[0][3] += a.x * w.w;
                    acc[1][0] += a.y * w.x; acc[1][1] += a.y * w.y; acc[1][2] += a.y * w.z; acc[1][3] += a.y * w.w;
                    acc[2][0] += a.z * w.x; acc[2][1] += a.z * w.y; acc[2][2] += a.z * w.z; acc[2][3] += a.z * w.w;
                    acc[3][0] += a.w * w.x; acc[3][1] += a.w * w.y; acc[3][2] += a.w * w.z; acc[3][3] += a.w * w.w;
                }
            }
            __syncthreads();
            // psum[og][pix(8)][64] @0..4096 (overwrites BAL/BBL, post-sync)
#pragma unroll
            for (int p = 0; p < 4; ++p)
#pragma unroll
                for (int q = 0; q < 4; ++q)
                    smem[og * 512 + (pxg + p) * 64 + dg + q] = acc[p][q];
            __syncthreads();
#pragma unroll
            for (int r = 0; r < 2; ++r) {
                int o = tid + r * 256;          // 0..511
                int pix = o >> 6, dl = o & 63;
                int d = d0 + dl;
                if (d < NDT) {
                    float s = 0.f;
#pragma unroll
                    for (int k = 0; k < 8; ++k) s += smem[k * 512 + o];
                    y8[(size_t)(b * 64 + pix0 + pix) * NDT + d] = s + b1[d];
                }
            }
            __syncthreads();
        }
        #undef BAL
        #undef BBL
    }
    group_barrier(cnt + 1, 48);

    // ================= Phase C: cluster (sub<4 -> head=sub) =================
    if (sub < 4) {
        #define SL(sp,p,c)  smem[(sp)*1600+(p)*25+(c)]
        #define Y2S(sp,m,c) smem[6400+((sp)*4+(m))*24+(c)]
        #define WBM(i,n,m)  smem[6784+((i)*64+(n))*5+(m)]
        #define AGG(mm,c)   smem[7424+(mm)*25+(c)]
        #define ANL(mm,c)   smem[7624+(mm)*24+(c)]
        #define NRM(mm)     smem[7816+(mm)]
        const int Bi = b, h = sub;
        const int lane = tid & 63, wid = tid >> 6;

        for (int idx = tid; idx < 4 * 64 * 6; idx += 256) {
            int q = idx % 6;
            int row = idx / 6;               // s'*64 + pix
            int pix = row & 63, sp = row >> 6;
            float4 v = *reinterpret_cast<const float4*>(
                &y8[(size_t)(Bi * 64 + pix) * NDT + (sp + 1) * NDIM + h * NHD + q * 4]);
            int c = q * 4;
            SL(sp, pix, c)     = v.x;
            SL(sp, pix, c + 1) = v.y;
            SL(sp, pix, c + 2) = v.z;
            SL(sp, pix, c + 3) = v.w;
        }
        __syncthreads();
        for (int idx = tid; idx < 4 * 4 * 24; idx += 256) {
            int c = idx % 24;
            int m = (idx / 24) & 3;
            int sp = idx / 96;
            int my = m >> 1, mx = m & 1;
            float acc = 0.f;
#pragma unroll
            for (int ry = 0; ry < 4; ++ry)
#pragma unroll
                for (int rx = 0; rx < 4; ++rx)
                    acc += SL(sp, (my * 4 + ry) * 8 + mx * 4 + rx, c);
            Y2S(sp, m, c) = acc * (1.f / 16.f);
        }
        __syncthreads();
        if (wid < 2) {
            const int i = wid, ksp = 2 * i;
            float ka[24];
            float sumk2 = 0.f;
#pragma unroll
            for (int c = 0; c < 24; ++c) { ka[c] = SL(ksp, lane, c); sumk2 += ka[c] * ka[c]; }
            float sim[4];
#pragma unroll
            for (int m = 0; m < 4; ++m) {
                float kc2 = 0.f, dt = 0.f;
#pragma unroll
                for (int c = 0; c < 24; ++c) {
                    float kv = Y2S(ksp, m, c);
                    kc2 += kv * kv; dt += kv * ka[c];
                }
                sim[m] = 2.f * dt - kc2 - sumk2;
            }
            float w[4];
            if (i == 0) {
                int am = 0; float bv = sim[0];
#pragma unroll
                for (int m = 1; m < 4; ++m) if (sim[m] > bv) { bv = sim[m]; am = m; }
#pragma unroll
                for (int m = 0; m < 4; ++m) w[m] = (m == am) ? 1.f : 0.f;
            } else {
                float mx = fmaxf(fmaxf(sim[0], sim[1]), fmaxf(sim[2], sim[3]));
                float sum = 0.f;
#pragma unroll
                for (int m = 0; m < 4; ++m) { w[m] = expf(sim[m] - mx); sum += w[m]; }
                float inv = 1.f / sum;
#pragma unroll
                for (int m = 0; m < 4; ++m) w[m] *= inv;
            }
#pragma unroll
            for (int m = 0; m < 4; ++m) WBM(i, lane, m) = w[m];
        }
        __syncthreads();
        if (tid < 200) {
            int i = tid / 100, rem = tid % 100;
            int m = rem / 25, c = rem % 25;
            int vsp = 1 + 2 * i;
            float s = 0.f;
#pragma unroll 8
            for (int n = 0; n < 64; ++n) {
                float wv = WBM(i, n, m);
                s += (c < 24) ? wv * SL(vsp, n, c) : wv;
            }
            AGG(i * 4 + m, c) = s;
        }
        __syncthreads();
        if (tid < 192) {
            int mm = tid / 24, c = tid % 24;
            int i = mm >> 2, m = mm & 3;
            AGG(mm, c) = (Y2S(1 + 2 * i, m, c) + AGG(mm, c)) / (1.f + AGG(mm, 24));
        }
        __syncthreads();
        if (tid < 8) {
            float s = 0.f;
#pragma unroll
            for (int c = 0; c < 24; ++c) s += AGG(tid, c) * AGG(tid, c);
            NRM(tid) = sqrtf(s) + 1e-6f;
        }
        __syncthreads();
        if (tid < 192) {
            int mm = tid / 24, c = tid % 24;
            ANL(mm, c) = AGG(mm, c) / NRM(mm);
        }
        __syncthreads();
        {
            const int n = lane;
            float pa[24]; float p2 = 0.f;
            const float* prow = &y8[(size_t)(Bi * 64 + n) * NDT + h * NHD];
#pragma unroll
            for (int q = 0; q < 6; ++q) {
                float4 v = *reinterpret_cast<const float4*>(prow + q * 4);
                pa[q * 4 + 0] = v.x; pa[q * 4 + 1] = v.y;
                pa[q * 4 + 2] = v.z; pa[q * 4 + 3] = v.w;
            }
#pragma unroll
            for (int c = 0; c < 24; ++c) p2 += pa[c] * pa[c];
            float pinv = 1.f / (sqrtf(p2) + 1e-6f);
            float s2[8];
#pragma unroll
            for (int mm = 0; mm < 8; ++mm) {
                float dt = 0.f;
#pragma unroll
                for (int c = 0; c < 24; ++c) dt += ANL(mm, c) * pa[c];
                s2[mm] = salpha[mm] * (dt * pinv) + sbeta[mm];
            }
            float mx = s2[0];
#pragma unroll
            for (int mm = 1; mm < 8; ++mm) mx = fmaxf(mx, s2[mm]);
            float sum = 0.f;
#pragma unroll
            for (int mm = 0; mm < 8; ++mm) { s2[mm] = expf(s2[mm] - mx); sum += s2[mm]; }
            float inv = 1.f / sum;
            const int c0 = wid * 6;
#pragma unroll
            for (int cc = 0; cc < 6; ++cc) {
                int c = c0 + cc;
                float v = 0.f;
#pragma unroll
                for (int mm = 0; mm < 8; ++mm) v += AGG(mm, c) * (s2[mm] * inv);
                o8[(size_t)(Bi * NDIM + h * NHD + c) * 64 + n] = v;
            }
        }
        #undef SL
        #undef Y2S
        #undef WBM
        #undef AGG
        #undef ANL
        #undef NRM
    }
    group_barrier(cnt + 2, 48);

    // ================= Phase D: proj2 + upsample (o-tiles strided) ========
    {
        #define DAL(d,n) smem[(d)*64+(n)]              // [96][64] @0..6144
        #define DWL(d,o) smem[6144+(d)*6+(o)]          // [96][6]  @6144..6720
        #define DZT(o,n) smem[6720+(o)*65+(n)]         // [6][65]  @6720..7110
        for (int t = sub; t < 64; t += 48) {
            const int o0 = t * 6;
            __syncthreads();
#pragma unroll
            for (int i = 0; i < 6; ++i) {
                int f = tid + i * 256;
                int d = f >> 4, ng = f & 15;
                *reinterpret_cast<float4*>(&DAL(d, ng * 4)) =
                    *reinterpret_cast<const float4*>(&o8[(size_t)(b * NDIM + d) * 64 + ng * 4]);
            }
            for (int idx = tid; idx < 96 * 6; idx += 256) {
                int d = idx / 6, o = idx % 6;
                DWL(d, o) = W2[d * NCIN + o0 + o];
            }
            __syncthreads();
            if (tid < 192) {                   // og = tid>>6 in 0..2, each 2 o's
                const int n = tid & 63, og = tid >> 6;
                float a0 = 0.f, a1 = 0.f;
#pragma unroll 8
                for (int d = 0; d < 96; ++d) {
                    float a = DAL(d, n);
                    a0 += a * DWL(d, og * 2 + 0);
                    a1 += a * DWL(d, og * 2 + 1);
                }
                DZT(og * 2 + 0, n) = a0;
                DZT(og * 2 + 1, n) = a1;
            }
            __syncthreads();
            if (tid < 96) {                    // slot = (ol 0..5, xq 0..15)
                const int ol = tid >> 4, xq = tid & 15;
                const float bias = b2[o0 + ol];

                float uxb = 0.125f * (float)(xq * 4) - 0.4375f;
                float uxbc = fminf(fmaxf(uxb, 0.f), 7.f);
                const int ixb = (int)uxbc;
                float wa[4], wbx[4], wc[4];
#pragma unroll
                for (int j = 0; j < 4; ++j) {
                    float ux  = 0.125f * (float)(xq * 4 + j) - 0.4375f;
                    float uxc = fminf(fmaxf(ux, 0.f), 7.f);
                    int ix0 = (int)uxc;
                    int ix1 = ix0 + 1 > 7 ? 7 : ix0 + 1;
                    float fx = uxc - (float)ix0;
                    int k0 = ix0 - ixb, k1 = ix1 - ixb;
                    wa[j]  = ((k0 == 0) ? (1.f - fx) : 0.f) + ((k1 == 0) ? fx : 0.f);
                    wbx[j] = ((k0 == 1) ? (1.f - fx) : 0.f) + ((k1 == 1) ? fx : 0.f);
                    wc[j]  = ((k1 == 2) ? fx : 0.f);
                }
                float zc0[8], zc1[8], zc2[8];
                {
                    const int i1 = ixb + 1 > 7 ? 7 : ixb + 1;
                    const int i2 = ixb + 2 > 7 ? 7 : ixb + 2;
#pragma unroll
                    for (int iy = 0; iy < 8; ++iy) {
                        zc0[iy] = DZT(ol, iy * 8 + ixb);
                        zc1[iy] = DZT(ol, iy * 8 + i1);
                        zc2[iy] = DZT(ol, iy * 8 + i2);
                    }
                }
                float* obase = out + (size_t)(b * NCIN + o0 + ol) * 4096 + xq * 4;
#pragma unroll
                for (int y = 0; y < 64; ++y) {
                    const float u  = 0.125f * (float)y - 0.4375f;
                    const float uc = fminf(fmaxf(u, 0.f), 7.f);
                    const int iy0 = (int)uc;
                    const int iy1 = iy0 + 1 > 7 ? 7 : iy0 + 1;
                    const float fy = uc - (float)iy0;
                    const float r0 = zc0[iy0] + fy * (zc0[iy1] - zc0[iy0]);
                    const float r1 = zc1[iy0] + fy * (zc1[iy1] - zc1[iy0]);
                    const float r2 = zc2[iy0] + fy * (zc2[iy1] - zc2[iy0]);
                    float4 v;
                    v.x = bias + wa[0] * r0 + wbx[0] * r1 + wc[0] * r2;
                    v.y = bias + wa[1] * r0 + wbx[1] * r1 + wc[1] * r2;
                    v.z = bias + wa[2] * r0 + wbx[2] * r1 + wc[2] * r2;
                    v.w = bias + wa[3] * r0 + wbx[3] * r1 + wc[3] * r2;
                    *reinterpret_cast<float4*>(obase + y * 64) = v;
                }
            }
        }
        #undef DAL
        #undef DWL
        #undef DZT
    }
}

// ===========================================================================
// PLAN B fallback: the proven 4-kernel pipeline (R5, 68.3 us).
// ===========================================================================
__global__ void __launch_bounds__(256) k_pool(const float* __restrict__ x,
                                              float* __restrict__ x8) {
    __shared__ float part[64][17];
    const int plane = blockIdx.x;
    const int t = threadIdx.x;
    const float4* xp = reinterpret_cast<const float4*>(x + (size_t)plane * 4096);
    const int chunk = t & 15;
    const int rloc  = t >> 4;
#pragma unroll
    for (int rr = 0; rr < 4; ++rr) {
        int row = rr * 16 + rloc;
        float4 v = xp[rr * 256 + t];
        part[row][chunk] = v.x + v.y + v.z + v.w;
    }
    __syncthreads();
    if (t < 64) {
        int py = t >> 3, px = t & 7;
        float s = 0.f;
#pragma unroll
        for (int r = 0; r < 8; ++r)
            s += part[py * 8 + r][px * 2] + part[py * 8 + r][px * 2 + 1];
        x8[(size_t)plane * 64 + t] = s * (1.f / 64.f);
    }
}

__global__ void __launch_bounds__(256) k_proj(const float* __restrict__ x8,
                                              const float* __restrict__ W1,
                                              const float* __restrict__ b1,
                                              float* __restrict__ y8) {
    __shared__ float AL[64][32];
    __shared__ float BL[64][64];
    const int b    = blockIdx.y >> 1;
    const int pix0 = (blockIdx.y & 1) * 32;
    const int d0   = blockIdx.x * 64;
    const int tid  = threadIdx.x;
    const int pxg  = (tid & 15) * 2;
    const int dg   = (tid >> 4) * 4;
    float acc[2][4] = {};
    for (int c0 = 0; c0 < 384; c0 += 64) {
        __syncthreads();
#pragma unroll
        for (int i = 0; i < 2; ++i) {
            int f = tid + i * 256;
            int c = f >> 3, pg = f & 7;
            *reinterpret_cast<float4*>(&AL[c][pg * 4]) =
                *reinterpret_cast<const float4*>(&x8[(b * 384 + c0 + c) * 64 + pix0 + pg * 4]);
        }
#pragma unroll
        for (int i = 0; i < 4; ++i) {
            int f = tid + i * 256;
            int c = f >> 4, jg = f & 15;
            int d = d0 + jg * 4;
            float4 v = make_float4(0.f, 0.f, 0.f, 0.f);
            if (d < NDT) v = *reinterpret_cast<const float4*>(&W1[(c0 + c) * NDT + d]);
            *reinterpret_cast<float4*>(&BL[c][jg * 4]) = v;
        }
        __syncthreads();
#pragma unroll 8
        for (int c = 0; c < 64; ++c) {
            float2 a = *reinterpret_cast<const float2*>(&AL[c][pxg]);
            float4 w = *reinterpret_cast<const float4*>(&BL[c][dg]);
            acc[0][0] += a.x * w.x; acc[0][1] += a.x * w.y;
            acc[0][2] += a.x * w.z; acc[0][3] += a.x * w.w;
            acc[1][0] += a.y * w.x; acc[1][1] += a.y * w.y;
            acc[1][2] += a.y * w.z; acc[1][3] += a.y * w.w;
        }
    }
    if (d0 + dg < NDT) {
        float4 bv = *reinterpret_cast<const float4*>(&b1[d0 + dg]);
#pragma unroll
        for (int p = 0; p < 2; ++p) {
            int pix = pix0 + pxg + p;
            float4 v = make_float4(acc[p][0] + bv.x, acc[p][1] + bv.y,
                                   acc[p][2] + bv.z, acc[p][3] + bv.w);
            *reinterpret_cast<float4*>(&y8[(size_t)(b * 64 + pix) * NDT + d0 + dg]) = v;
        }
    }
}

__global__ void __launch_bounds__(256) k_cluster(const float* __restrict__ y8,
                                                 const float* __restrict__ salpha,
                                                 const float* __restrict__ sbeta,
                                                 float* __restrict__ out8) {
    __shared__ float sl[5][64][25];
    __shared__ float y2s[5][4][24];
    __shared__ float wb[2][64][5];
    __shared__ float aggL[8][25];
    __shared__ float anL[8][24];
    __shared__ float normL[8];

    const int bp = blockIdx.x;
    const int Bi = bp >> 2, h = bp & 3;
    const int tid = threadIdx.x;
    const int lane = tid & 63, wid = tid >> 6;

    for (int idx = tid; idx < 5 * 64 * 6; idx += 256) {
        int q = idx % 6;
        int row = idx / 6;
        int pix = row & 63, s = row >> 6;
        float4 v = *reinterpret_cast<const float4*>(
            &y8[(size_t)(Bi * 64 + pix) * NDT + s * NDIM + h * NHD + q * 4]);
        int c = q * 4;
        sl[s][pix][c]     = v.x;
        sl[s][pix][c + 1] = v.y;
        sl[s][pix][c + 2] = v.z;
        sl[s][pix][c + 3] = v.w;
    }
    __syncthreads();
    for (int idx = tid; idx < 5 * 4 * 24; idx += 256) {
        int c = idx % 24;
        int m = (idx / 24) & 3;
        int s = idx / 96;
        int my = m >> 1, mx = m & 1;
        float acc = 0.f;
#pragma unroll
        for (int ry = 0; ry < 4; ++ry)
#pragma unroll
            for (int rx = 0; rx < 4; ++rx)
                acc += sl[s][(my * 4 + ry) * 8 + mx * 4 + rx][c];
        y2s[s][m][c] = acc * (1.f / 16.f);
    }
    __syncthreads();
    if (wid < 2) {
        const int i = wid, ks = 1 + 2 * i;
        float ka[24];
        float sumk2 = 0.f;
#pragma unroll
        for (int c = 0; c < 24; ++c) { ka[c] = sl[ks][lane][c]; sumk2 += ka[c] * ka[c]; }
        float sim[4];
#pragma unroll
        for (int m = 0; m < 4; ++m) {
            float kc2 = 0.f, dt = 0.f;
#pragma unroll
            for (int c = 0; c < 24; ++c) {
                float kv = y2s[ks][m][c];
                kc2 += kv * kv; dt += kv * ka[c];
            }
            sim[m] = 2.f * dt - kc2 - sumk2;
        }
        float w[4];
        if (i == 0) {
            int am = 0; float bv = sim[0];
#pragma unroll
            for (int m = 1; m < 4; ++m) if (sim[m] > bv) { bv = sim[m]; am = m; }
#pragma unroll
            for (int m = 0; m < 4; ++m) w[m] = (m == am) ? 1.f : 0.f;
        } else {
            float mx = fmaxf(fmaxf(sim[0], sim[1]), fmaxf(sim[2], sim[3]));
            float sum = 0.f;
#pragma unroll
            for (int m = 0; m < 4; ++m) { w[m] = expf(sim[m] - mx); sum += w[m]; }
            float inv = 1.f / sum;
#pragma unroll
            for (int m = 0; m < 4; ++m) w[m] *= inv;
        }
#pragma unroll
        for (int m = 0; m < 4; ++m) wb[i][lane][m] = w[m];
    }
    __syncthreads();
    if (tid < 200) {
        int i = tid / 100, rem = tid % 100;
        int m = rem / 25, c = rem % 25;
        int vs = 2 + 2 * i;
        float s = 0.f;
#pragma unroll 8
        for (int n = 0; n < 64; ++n) {
            float wv = wb[i][n][m];
            s += (c < 24) ? wv * sl[vs][n][c] : wv;
        }
        aggL[i * 4 + m][c] = s;
    }
    __syncthreads();
    if (tid < 192) {
        int mm = tid / 24, c = tid % 24;
        int i = mm >> 2, m = mm & 3;
        aggL[mm][c] = (y2s[2 + 2 * i][m][c] + aggL[mm][c]) / (1.f + aggL[mm][24]);
    }
    __syncthreads();
    if (tid < 8) {
        float s = 0.f;
#pragma unroll
        for (int c = 0; c < 24; ++c) s += aggL[tid][c] * aggL[tid][c];
        normL[tid] = sqrtf(s) + 1e-6f;
    }
    __syncthreads();
    if (tid < 192) {
        int mm = tid / 24, c = tid % 24;
        anL[mm][c] = aggL[mm][c] / normL[mm];
    }
    __syncthreads();
    {
        const int n = lane;
        float pa[24]; float p2 = 0.f;
#pragma unroll
        for (int c = 0; c < 24; ++c) { pa[c] = sl[0][n][c]; p2 += pa[c] * pa[c]; }
        float pinv = 1.f / (sqrtf(p2) + 1e-6f);
        float s2[8];
#pragma unroll
        for (int mm = 0; mm < 8; ++mm) {
            float dt = 0.f;
#pragma unroll
            for (int c = 0; c < 24; ++c) dt += anL[mm][c] * pa[c];
            s2[mm] = salpha[mm] * (dt * pinv) + sbeta[mm];
        }
        float mx = s2[0];
#pragma unroll
        for (int mm = 1; mm < 8; ++mm) mx = fmaxf(mx, s2[mm]);
        float sum = 0.f;
#pragma unroll
        for (int mm = 0; mm < 8; ++mm) { s2[mm] = expf(s2[mm] - mx); sum += s2[mm]; }
        float inv = 1.f / sum;
        const int c0 = wid * 6;
#pragma unroll
        for (int cc = 0; cc < 6; ++cc) {
            int c = c0 + cc;
            float v = 0.f;
#pragma unroll
            for (int mm = 0; mm < 8; ++mm) v += aggL[mm][c] * (s2[mm] * inv);
            out8[(size_t)(Bi * NDIM + h * NHD + c) * 64 + n] = v;
        }
    }
}

__global__ void __launch_bounds__(256) k_proj2up(const float* __restrict__ out8,
                                                 const float* __restrict__ W2,
                                                 const float* __restrict__ b2,
                                                 float* __restrict__ out) {
    __shared__ float AL[96][64];
    __shared__ float WL[96][24];
    __shared__ float ZT[24][65];
    const int Bi = blockIdx.y;
    const int o0 = blockIdx.x * 24;
    const int tid = threadIdx.x;

#pragma unroll
    for (int i = 0; i < 6; ++i) {
        int f = tid + i * 256;
        int d = f >> 4, ng = f & 15;
        *reinterpret_cast<float4*>(&AL[d][ng * 4]) =
            *reinterpret_cast<const float4*>(&out8[(size_t)(Bi * NDIM + d) * 64 + ng * 4]);
    }
    for (int idx = tid; idx < 96 * 6; idx += 256) {
        int d = idx / 6, q = idx % 6;
        *reinterpret_cast<float4*>(&WL[d][q * 4]) =
            *reinterpret_cast<const float4*>(&W2[d * NCIN + o0 + q * 4]);
    }
    __syncthreads();
    {
        const int n = tid & 63, og = tid >> 6;
        float a0 = 0.f, a1 = 0.f, a2 = 0.f, a3 = 0.f, a4 = 0.f, a5 = 0.f;
#pragma unroll 8
        for (int d = 0; d < 96; ++d) {
            float a = AL[d][n];
            float2 w01 = *reinterpret_cast<const float2*>(&WL[d][og * 6 + 0]);
            float2 w23 = *reinterpret_cast<const float2*>(&WL[d][og * 6 + 2]);
            float2 w45 = *reinterpret_cast<const float2*>(&WL[d][og * 6 + 4]);
            a0 += a * w01.x; a1 += a * w01.y;
            a2 += a * w23.x; a3 += a * w23.y;
            a4 += a * w45.x; a5 += a * w45.y;
        }
        ZT[og * 6 + 0][n] = a0;
        ZT[og * 6 + 1][n] = a1;
        ZT[og * 6 + 2][n] = a2;
        ZT[og * 6 + 3][n] = a3;
        ZT[og * 6 + 4][n] = a4;
        ZT[og * 6 + 5][n] = a5;
    }
    __syncthreads();
#pragma unroll
    for (int pass = 0; pass < 2; ++pass) {
        int slot = pass * 256 + tid;
        if (slot < 24 * 16) {
            const int ol = slot >> 4, xq = slot & 15;
            const float bias = b2[o0 + ol];

            float uxb = 0.125f * (float)(xq * 4) - 0.4375f;
            float uxbc = fminf(fmaxf(uxb, 0.f), 7.f);
            const int ixb = (int)uxbc;
            float wa[4], wbx[4], wc[4];
#pragma unroll
            for (int j = 0; j < 4; ++j) {
                float ux  = 0.125f * (float)(xq * 4 + j) - 0.4375f;
                float uxc = fminf(fmaxf(ux, 0.f), 7.f);
                int ix0 = (int)uxc;
                int ix1 = ix0 + 1 > 7 ? 7 : ix0 + 1;
                float fx = uxc - (float)ix0;
                int k0 = ix0 - ixb, k1 = ix1 - ixb;
                wa[j]  = ((k0 == 0) ? (1.f - fx) : 0.f) + ((k1 == 0) ? fx : 0.f);
                wbx[j] = ((k0 == 1) ? (1.f - fx) : 0.f) + ((k1 == 1) ? fx : 0.f);
                wc[j]  = ((k1 == 2) ? fx : 0.f);
            }
            float zc0[8], zc1[8], zc2[8];
            {
                const int i1 = ixb + 1 > 7 ? 7 : ixb + 1;
                const int i2 = ixb + 2 > 7 ? 7 : ixb + 2;
#pragma unroll
                for (int iy = 0; iy < 8; ++iy) {
                    zc0[iy] = ZT[ol][iy * 8 + ixb];
                    zc1[iy] = ZT[ol][iy * 8 + i1];
                    zc2[iy] = ZT[ol][iy * 8 + i2];
                }
            }
            float* obase = out + (size_t)(Bi * NCIN + o0 + ol) * 4096 + xq * 4;
#pragma unroll
            for (int y = 0; y < 64; ++y) {
                const float u  = 0.125f * (float)y - 0.4375f;
                const float uc = fminf(fmaxf(u, 0.f), 7.f);
                const int iy0 = (int)uc;
                const int iy1 = iy0 + 1 > 7 ? 7 : iy0 + 1;
                const float fy = uc - (float)iy0;
                const float r0 = zc0[iy0] + fy * (zc0[iy1] - zc0[iy0]);
                const float r1 = zc1[iy0] + fy * (zc1[iy1] - zc1[iy0]);
                const float r2 = zc2[iy0] + fy * (zc2[iy1] - zc2[iy0]);
                float4 v;
                v.x = bias + wa[0] * r0 + wbx[0] * r1 + wc[0] * r2;
                v.y = bias + wa[1] * r0 + wbx[1] * r1 + wc[1] * r2;
                v.z = bias + wa[2] * r0 + wbx[2] * r1 + wc[2] * r2;
                v.w = bias + wa[3] * r0 + wbx[3] * r1 + wc[3] * r2;
                *reinterpret_cast<float4*>(obase + y * 64) = v;
            }
        }
    }
}

// ---------------------------------------------------------------------------
extern "C" void kernel_launch(void* const* d_in, const int* in_sizes, int n_in,
                              void* d_out, int out_size, void* d_ws, size_t ws_size,
                              hipStream_t stream) {
    const float* x  = (const float*)d_in[0];
    const float* W1 = (const float*)d_in[1];
    const float* b1 = (const float*)d_in[2];
    const float* W2 = (const float*)d_in[3];
    const float* b2 = (const float*)d_in[4];
    const float* sa = (const float*)d_in[5];
    const float* sb = (const float*)d_in[6];
    float* out = (float*)d_out;

    float* x8 = (float*)d_ws;                 // 16*384*64 = 393216 f
    float* y8 = x8 + 16 * 384 * 64;           // 1024*480  = 491520 f
    float* o8 = y8 + 1024 * 480;              // 16*96*64  =  98304 f
    int* flags = (int*)(o8 + 16 * 96 * 64);   // 48 ints

    hipMemsetAsync(flags, 0, 64 * sizeof(int), stream);

    void* args[] = {(void*)&x, (void*)&W1, (void*)&b1, (void*)&W2, (void*)&b2,
                    (void*)&sa, (void*)&sb, (void*)&out, (void*)&x8, (void*)&y8,
                    (void*)&o8, (void*)&flags};
    hipError_t err = hipLaunchCooperativeKernel((const void*)k_fused, dim3(768),
                                                dim3(256), args, 0, stream);
    if (err != hipSuccess) {
        // PLAN B: proven 4-kernel pipeline
        k_pool<<<dim3(16 * 384), dim3(256), 0, stream>>>(x, x8);
        k_proj<<<dim3(8, 32), dim3(256), 0, stream>>>(x8, W1, b1, y8);
        k_cluster<<<dim3(64), dim3(256), 0, stream>>>(y8, sa, sb, o8);
        k_proj2up<<<dim3(16, 16), dim3(256), 0, stream>>>(o8, W2, b2, out);
    }
}

// Round 10
// 87.062 us; speedup vs baseline: 8.0651x; 8.0651x over previous
//
#include <hip/hip_runtime.h>
#include <math.h>

#define NB     16
#define NCIN   384
#define NHD    24
#define NDIM   96
#define NSTR   5
#define NDT    480

// ---------------------------------------------------------------------------
// Kernel 1: 8x8 average pool (proven R5 form): block = one (b,c) plane,
// contiguous float4 reads, LDS partial reduce.
// ---------------------------------------------------------------------------
__global__ void __launch_bounds__(256) k_pool(const float* __restrict__ x,
                                              float* __restrict__ x8) {
    __shared__ float part[64][17];
    const int plane = blockIdx.x;
    const int t = threadIdx.x;
    const float4* xp = reinterpret_cast<const float4*>(x + (size_t)plane * 4096);
    const int chunk = t & 15;
    const int rloc  = t >> 4;
#pragma unroll
    for (int rr = 0; rr < 4; ++rr) {
        int row = rr * 16 + rloc;
        float4 v = xp[rr * 256 + t];
        part[row][chunk] = v.x + v.y + v.z + v.w;
    }
    __syncthreads();
    if (t < 64) {
        int py = t >> 3, px = t & 7;
        float s = 0.f;
#pragma unroll
        for (int r = 0; r < 8; ++r)
            s += part[py * 8 + r][px * 2] + part[py * 8 + r][px * 2 + 1];
        x8[(size_t)plane * 64 + t] = s * (1.f / 64.f);
    }
}

// ---------------------------------------------------------------------------
// Kernel 2: proj (proven R2/R5 form). grid (8 d-tiles, 32 b*pixhalf),
// 256 threads, tile 32pix x 64d, thread = 2pix x 4d.
// ---------------------------------------------------------------------------
__global__ void __launch_bounds__(256) k_proj(const float* __restrict__ x8,
                                              const float* __restrict__ W1,
                                              const float* __restrict__ b1,
                                              float* __restrict__ y8) {
    __shared__ float AL[64][32];
    __shared__ float BL[64][64];
    const int b    = blockIdx.y >> 1;
    const int pix0 = (blockIdx.y & 1) * 32;
    const int d0   = blockIdx.x * 64;
    const int tid  = threadIdx.x;
    const int pxg  = (tid & 15) * 2;
    const int dg   = (tid >> 4) * 4;
    float acc[2][4] = {};
    for (int c0 = 0; c0 < 384; c0 += 64) {
        __syncthreads();
#pragma unroll
        for (int i = 0; i < 2; ++i) {
            int f = tid + i * 256;
            int c = f >> 3, pg = f & 7;
            *reinterpret_cast<float4*>(&AL[c][pg * 4]) =
                *reinterpret_cast<const float4*>(&x8[(b * 384 + c0 + c) * 64 + pix0 + pg * 4]);
        }
#pragma unroll
        for (int i = 0; i < 4; ++i) {
            int f = tid + i * 256;
            int c = f >> 4, jg = f & 15;
            int d = d0 + jg * 4;
            float4 v = make_float4(0.f, 0.f, 0.f, 0.f);
            if (d < NDT) v = *reinterpret_cast<const float4*>(&W1[(c0 + c) * NDT + d]);
            *reinterpret_cast<float4*>(&BL[c][jg * 4]) = v;
        }
        __syncthreads();
#pragma unroll 8
        for (int c = 0; c < 64; ++c) {
            float2 a = *reinterpret_cast<const float2*>(&AL[c][pxg]);
            float4 w = *reinterpret_cast<const float4*>(&BL[c][dg]);
            acc[0][0] += a.x * w.x; acc[0][1] += a.x * w.y;
            acc[0][2] += a.x * w.z; acc[0][3] += a.x * w.w;
            acc[1][0] += a.y * w.x; acc[1][1] += a.y * w.y;
            acc[1][2] += a.y * w.z; acc[1][3] += a.y * w.w;
        }
    }
    if (d0 + dg < NDT) {
        float4 bv = *reinterpret_cast<const float4*>(&b1[d0 + dg]);
#pragma unroll
        for (int p = 0; p < 2; ++p) {
            int pix = pix0 + pxg + p;
            float4 v = make_float4(acc[p][0] + bv.x, acc[p][1] + bv.y,
                                   acc[p][2] + bv.z, acc[p][3] + bv.w);
            *reinterpret_cast<float4*>(&y8[(size_t)(b * 64 + pix) * NDT + d0 + dg]) = v;
        }
    }
}

// ---------------------------------------------------------------------------
// Kernel 3 (fused cluster + proj2 + upsample): grid (16 o-tiles, 16 b),
// 256 threads. Each block computes the (tiny) clustering for ALL 4 heads
// (redundant x16 per batch, from L2-hot y8), then
//   G[k=h*8+mm][o] = sum_c W2[h*24+c][o0+o] * agg[k][c]        (32x24, K=24)
//   ZT[o][n]       = sum_k G[k][o] * asg[k][n]                  (24x64, K=32)
// then the proven bilinear upsample writes out (HBM-write-bound phase).
// Cluster internals lifted verbatim from the R9-verified kernel.
// ---------------------------------------------------------------------------
__global__ void __launch_bounds__(256) k_cpu(const float* __restrict__ y8,
                                             const float* __restrict__ W2,
                                             const float* __restrict__ b2,
                                             const float* __restrict__ salpha,
                                             const float* __restrict__ sbeta,
                                             float* __restrict__ out) {
    __shared__ __align__(16) float smem[12968];
    #define SL(sp,p,c)  smem[(sp)*1600+(p)*25+(c)]       // 6400 @0 (reused/head)
    #define Y2S(sp,m,c) smem[6400+((sp)*4+(m))*24+(c)]   // 384
    #define WBM(i,n,m)  smem[6784+((i)*64+(n))*5+(m)]    // 640
    #define AGG(mm,c)   smem[7424+(mm)*25+(c)]           // 200
    #define NRM(mm)     smem[7624+(mm)]                  // 8
    #define ANL(mm,c)   smem[7632+(mm)*24+(c)]           // 192
    #define AGA(k,c)    smem[7824+(k)*24+(c)]            // 768  agg_all
    #define ASG(k,n)    smem[8592+(k)*64+(n)]            // 2048 asg_all
    #define GM(k,o)     smem[10640+(k)*24+(o)]           // 768
    #define ZT(o,n)     smem[11408+(o)*65+(n)]           // 1560
    #define W2L(d,o)    smem[(d)*24+(o)]                 // 2304 (reuses SL area)

    const int b  = blockIdx.y;
    const int o0 = blockIdx.x * 24;
    const int tid = threadIdx.x;
    const int lane = tid & 63, wid = tid >> 6;

    // ================= clustering for all 4 heads =================
    for (int h = 0; h < 4; ++h) {
        if (h) __syncthreads();            // protect SL/WBM/AGG reuse
        for (int idx = tid; idx < 4 * 64 * 6; idx += 256) {
            int q = idx % 6;
            int row = idx / 6;             // sp*64 + pix
            int pix = row & 63, sp = row >> 6;
            float4 v = *reinterpret_cast<const float4*>(
                &y8[(size_t)(b * 64 + pix) * NDT + (sp + 1) * NDIM + h * NHD + q * 4]);
            int c = q * 4;
            SL(sp, pix, c)     = v.x;
            SL(sp, pix, c + 1) = v.y;
            SL(sp, pix, c + 2) = v.z;
            SL(sp, pix, c + 3) = v.w;
        }
        __syncthreads();
        for (int idx = tid; idx < 4 * 4 * 24; idx += 256) {
            int c = idx % 24;
            int m = (idx / 24) & 3;
            int sp = idx / 96;
            int my = m >> 1, mx = m & 1;
            float acc = 0.f;
#pragma unroll
            for (int ry = 0; ry < 4; ++ry)
#pragma unroll
                for (int rx = 0; rx < 4; ++rx)
                    acc += SL(sp, (my * 4 + ry) * 8 + mx * 4 + rx, c);
            Y2S(sp, m, c) = acc * (1.f / 16.f);
        }
        __syncthreads();
        if (wid < 2) {
            const int i = wid, ksp = 2 * i;          // k-stream of module i
            float ka[24];
            float sumk2 = 0.f;
#pragma unroll
            for (int c = 0; c < 24; ++c) { ka[c] = SL(ksp, lane, c); sumk2 += ka[c] * ka[c]; }
            float sim[4];
#pragma unroll
            for (int m = 0; m < 4; ++m) {
                float kc2 = 0.f, dt = 0.f;
#pragma unroll
                for (int c = 0; c < 24; ++c) {
                    float kv = Y2S(ksp, m, c);
                    kc2 += kv * kv; dt += kv * ka[c];
                }
                sim[m] = 2.f * dt - kc2 - sumk2;
            }
            float w[4];
            if (i == 0) {
                int am = 0; float bv = sim[0];
#pragma unroll
                for (int m = 1; m < 4; ++m) if (sim[m] > bv) { bv = sim[m]; am = m; }
#pragma unroll
                for (int m = 0; m < 4; ++m) w[m] = (m == am) ? 1.f : 0.f;
            } else {
                float mx = fmaxf(fmaxf(sim[0], sim[1]), fmaxf(sim[2], sim[3]));
                float sum = 0.f;
#pragma unroll
                for (int m = 0; m < 4; ++m) { w[m] = expf(sim[m] - mx); sum += w[m]; }
                float inv = 1.f / sum;
#pragma unroll
                for (int m = 0; m < 4; ++m) w[m] *= inv;
            }
#pragma unroll
            for (int m = 0; m < 4; ++m) WBM(i, lane, m) = w[m];
        }
        __syncthreads();
        if (tid < 200) {
            int i = tid / 100, rem = tid % 100;
            int m = rem / 25, c = rem % 25;
            int vsp = 1 + 2 * i;             // v-stream of module i
            float s = 0.f;
#pragma unroll 8
            for (int n = 0; n < 64; ++n) {
                float wv = WBM(i, n, m);
                s += (c < 24) ? wv * SL(vsp, n, c) : wv;
            }
            AGG(i * 4 + m, c) = s;
        }
        __syncthreads();
        if (tid < 192) {
            int mm = tid / 24, c = tid % 24;
            int i = mm >> 2, m = mm & 3;
            AGA(h * 8 + mm, c) = (Y2S(1 + 2 * i, m, c) + AGG(mm, c)) / (1.f + AGG(mm, 24));
        }
        __syncthreads();
        if (tid < 8) {
            float s = 0.f;
#pragma unroll
            for (int c = 0; c < 24; ++c) s += AGA(h * 8 + tid, c) * AGA(h * 8 + tid, c);
            NRM(tid) = sqrtf(s) + 1e-6f;
        }
        __syncthreads();
        if (tid < 192) {
            int mm = tid / 24, c = tid % 24;
            ANL(mm, c) = AGA(h * 8 + mm, c) / NRM(mm);
        }
        __syncthreads();
        if (wid == 0) {                       // one wave: per-token softmax
            const int n = lane;
            float pa[24]; float p2 = 0.f;
            const float* prow = &y8[(size_t)(b * 64 + n) * NDT + h * NHD];
#pragma unroll
            for (int q = 0; q < 6; ++q) {
                float4 v = *reinterpret_cast<const float4*>(prow + q * 4);
                pa[q * 4 + 0] = v.x; pa[q * 4 + 1] = v.y;
                pa[q * 4 + 2] = v.z; pa[q * 4 + 3] = v.w;
            }
#pragma unroll
            for (int c = 0; c < 24; ++c) p2 += pa[c] * pa[c];
            float pinv = 1.f / (sqrtf(p2) + 1e-6f);
            float s2[8];
#pragma unroll
            for (int mm = 0; mm < 8; ++mm) {
                float dt = 0.f;
#pragma unroll
                for (int c = 0; c < 24; ++c) dt += ANL(mm, c) * pa[c];
                s2[mm] = salpha[mm] * (dt * pinv) + sbeta[mm];
            }
            float mx = s2[0];
#pragma unroll
            for (int mm = 1; mm < 8; ++mm) mx = fmaxf(mx, s2[mm]);
            float sum = 0.f;
#pragma unroll
            for (int mm = 0; mm < 8; ++mm) { s2[mm] = expf(s2[mm] - mx); sum += s2[mm]; }
            float inv = 1.f / sum;
#pragma unroll
            for (int mm = 0; mm < 8; ++mm)
                ASG(h * 8 + mm, n) = s2[mm] * inv;
        }
    }
    __syncthreads();

    // ================= G = W2^T (slice) . agg  (32 x 24) =================
    // stage W2 slice [96][24] into the (now free) SL area, float4 loads
    for (int idx = tid; idx < 96 * 6; idx += 256) {
        int d = idx / 6, q = idx % 6;
        float4 v = *reinterpret_cast<const float4*>(&W2[d * NCIN + o0 + q * 4]);
        W2L(d, q * 4 + 0) = v.x; W2L(d, q * 4 + 1) = v.y;
        W2L(d, q * 4 + 2) = v.z; W2L(d, q * 4 + 3) = v.w;
    }
    __syncthreads();
#pragma unroll
    for (int r = 0; r < 3; ++r) {             // 768 slots = 256 * 3
        int idx = tid + r * 256;
        int k = idx / 24, o = idx % 24;
        int dbase = (k >> 3) * 24;             // head row block in W2
        float s = 0.f;
#pragma unroll
        for (int c = 0; c < 24; ++c)
            s += AGA(k, c) * W2L(dbase + c, o);
        GM(k, o) = s;
    }
    __syncthreads();

    // ================= ZT[o][n] = sum_k G[k][o] * asg[k][n] =================
#pragma unroll
    for (int r = 0; r < 2; ++r) {             // 384 slots (o, n-group of 4)
        int idx = tid + r * 256;
        if (idx < 24 * 16) {
            int o = idx >> 4, ng = idx & 15;
            float z0 = 0.f, z1 = 0.f, z2 = 0.f, z3 = 0.f;
#pragma unroll
            for (int k = 0; k < 32; ++k) {
                float g = GM(k, o);
                float4 a = *reinterpret_cast<const float4*>(&ASG(k, ng * 4));
                z0 += g * a.x; z1 += g * a.y; z2 += g * a.z; z3 += g * a.w;
            }
            ZT(o, ng * 4 + 0) = z0;
            ZT(o, ng * 4 + 1) = z1;
            ZT(o, ng * 4 + 2) = z2;
            ZT(o, ng * 4 + 3) = z3;
        }
    }
    __syncthreads();

    // ================= bilinear upsample + bias (proven) =================
#pragma unroll
    for (int pass = 0; pass < 2; ++pass) {
        int slot = pass * 256 + tid;
        if (slot < 24 * 16) {
            const int ol = slot >> 4, xq = slot & 15;
            const float bias = b2[o0 + ol];

            float uxb = 0.125f * (float)(xq * 4) - 0.4375f;
            float uxbc = fminf(fmaxf(uxb, 0.f), 7.f);
            const int ixb = (int)uxbc;
            float wa[4], wbx[4], wc[4];
#pragma unroll
            for (int j = 0; j < 4; ++j) {
                float ux  = 0.125f * (float)(xq * 4 + j) - 0.4375f;
                float uxc = fminf(fmaxf(ux, 0.f), 7.f);
                int ix0 = (int)uxc;
                int ix1 = ix0 + 1 > 7 ? 7 : ix0 + 1;
                float fx = uxc - (float)ix0;
                int k0 = ix0 - ixb, k1 = ix1 - ixb;
                wa[j]  = ((k0 == 0) ? (1.f - fx) : 0.f) + ((k1 == 0) ? fx : 0.f);
                wbx[j] = ((k0 == 1) ? (1.f - fx) : 0.f) + ((k1 == 1) ? fx : 0.f);
                wc[j]  = ((k1 == 2) ? fx : 0.f);
            }
            float zc0[8], zc1[8], zc2[8];
            {
                const int i1 = ixb + 1 > 7 ? 7 : ixb + 1;
                const int i2 = ixb + 2 > 7 ? 7 : ixb + 2;
#pragma unroll
                for (int iy = 0; iy < 8; ++iy) {
                    zc0[iy] = ZT(ol, iy * 8 + ixb);
                    zc1[iy] = ZT(ol, iy * 8 + i1);
                    zc2[iy] = ZT(ol, iy * 8 + i2);
                }
            }
            float* obase = out + (size_t)(b * NCIN + o0 + ol) * 4096 + xq * 4;
#pragma unroll
            for (int y = 0; y < 64; ++y) {
                const float u  = 0.125f * (float)y - 0.4375f;
                const float uc = fminf(fmaxf(u, 0.f), 7.f);
                const int iy0 = (int)uc;
                const int iy1 = iy0 + 1 > 7 ? 7 : iy0 + 1;
                const float fy = uc - (float)iy0;
                const float r0 = zc0[iy0] + fy * (zc0[iy1] - zc0[iy0]);
                const float r1 = zc1[iy0] + fy * (zc1[iy1] - zc1[iy0]);
                const float r2 = zc2[iy0] + fy * (zc2[iy1] - zc2[iy0]);
                float4 v;
                v.x = bias + wa[0] * r0 + wbx[0] * r1 + wc[0] * r2;
                v.y = bias + wa[1] * r0 + wbx[1] * r1 + wc[1] * r2;
                v.z = bias + wa[2] * r0 + wbx[2] * r1 + wc[2] * r2;
                v.w = bias + wa[3] * r0 + wbx[3] * r1 + wc[3] * r2;
                *reinterpret_cast<float4*>(obase + y * 64) = v;
            }
        }
    }
    #undef SL
    #undef Y2S
    #undef WBM
    #undef AGG
    #undef NRM
    #undef ANL
    #undef AGA
    #undef ASG
    #undef GM
    #undef ZT
    #undef W2L
}

// ---------------------------------------------------------------------------
extern "C" void kernel_launch(void* const* d_in, const int* in_sizes, int n_in,
                              void* d_out, int out_size, void* d_ws, size_t ws_size,
                              hipStream_t stream) {
    const float* x  = (const float*)d_in[0];
    const float* W1 = (const float*)d_in[1];
    const float* b1 = (const float*)d_in[2];
    const float* W2 = (const float*)d_in[3];
    const float* b2 = (const float*)d_in[4];
    const float* sa = (const float*)d_in[5];
    const float* sb = (const float*)d_in[6];
    float* out = (float*)d_out;

    float* x8 = (float*)d_ws;                 // 16*384*64 = 393216 f
    float* y8 = x8 + 16 * 384 * 64;           // 1024*480  = 491520 f

    k_pool<<<dim3(16 * 384), dim3(256), 0, stream>>>(x, x8);
    k_proj<<<dim3(8, 32), dim3(256), 0, stream>>>(x8, W1, b1, y8);
    k_cpu<<<dim3(16, 16), dim3(256), 0, stream>>>(y8, W2, b2, sa, sb, out);
}